// Round 3
// baseline (45.837 us; speedup 1.0000x reference)
//
#include <hip/hip_runtime.h>
#include <hip/hip_bf16.h>

// Problem constants (from reference setup_inputs: b=4, s=4096, d=2048, CAPACITY=0.5)
#define BATCH 4
#define SEQ   4096
#define DMODEL 2048
#define KSEL  2048   // max(1, int(SEQ*0.5))
#define ROWS_PER_WAVE 4

// ---------------------------------------------------------------------------
// Kernel 1: logits = x @ gate_w (fp64 accumulate), weights = sigmoid(logits)
// 1024 blocks x 256 threads; each 64-lane wave owns 4 consecutive rows.
// gate_w slice (8 float4/lane) is loaded ONCE per wave into registers and
// reused across all 4 rows. Row loop unrolled so row r+1's 8 float4 loads
// overlap row r's fp64 FMAs. One 4-way-interleaved shuffle reduction at the
// end. 4 blocks/CU (16 waves) with ~8 loads in flight each -> HBM-bound.
// ---------------------------------------------------------------------------
__global__ __launch_bounds__(256, 4) void logits_kernel(
    const float* __restrict__ x,
    const float* __restrict__ gate_w,
    float* __restrict__ logits,     // [BATCH*SEQ] in workspace
    float* __restrict__ weights)    // [BATCH*SEQ] -> d_out + BATCH*SEQ
{
    const int wave = threadIdx.x >> 6;
    const int lane = threadIdx.x & 63;
    const int wid  = blockIdx.x * 4 + wave;          // 0 .. 4095
    const int row0 = wid * ROWS_PER_WAVE;            // 4 consecutive rows

    const float4* wr = reinterpret_cast<const float4*>(gate_w);
    float4 wv[8];
#pragma unroll
    for (int t = 0; t < 8; ++t) wv[t] = wr[t * 64 + lane];

    double rsum[ROWS_PER_WAVE];
#pragma unroll
    for (int r = 0; r < ROWS_PER_WAVE; ++r) {
        const float4* xr =
            reinterpret_cast<const float4*>(x + (size_t)(row0 + r) * DMODEL);
        float4 xv[8];
#pragma unroll
        for (int t = 0; t < 8; ++t) xv[t] = xr[t * 64 + lane];

        double a0 = 0.0, a1 = 0.0, a2 = 0.0, a3 = 0.0;
#pragma unroll
        for (int t = 0; t < 8; ++t) {
            a0 += (double)xv[t].x * (double)wv[t].x;
            a1 += (double)xv[t].y * (double)wv[t].y;
            a2 += (double)xv[t].z * (double)wv[t].z;
            a3 += (double)xv[t].w * (double)wv[t].w;
        }
        rsum[r] = (a0 + a1) + (a2 + a3);
    }

    // 64-lane reduction, 4 independent chains interleaved
#pragma unroll
    for (int off = 32; off > 0; off >>= 1) {
#pragma unroll
        for (int r = 0; r < ROWS_PER_WAVE; ++r)
            rsum[r] += __shfl_down(rsum[r], off, 64);
    }

    if (lane == 0) {
#pragma unroll
        for (int r = 0; r < ROWS_PER_WAVE; ++r) {
            float l = (float)rsum[r];
            logits[row0 + r]  = l;
            weights[row0 + r] = 1.0f / (1.0f + expf(-l));
        }
    }
}

// ---------------------------------------------------------------------------
// Kernel 2 (merged select + finalize):
//   blocks 0 .. BATCH*64-1 : top-K mask via exact rank counting
//   block  BATCH*64        : aux_loss = unbiased variance of weights
// Mask blocks: full 4096-float row staged in LDS; thread (e = tid&63,
// slice = tid>>6) compares its element against one quarter of the row via
// wave-uniform float4 LDS reads (broadcast, conflict-free). Tie-break
// matches jax.lax.top_k (lower index wins) via the rare-path recount.
// ---------------------------------------------------------------------------
__global__ __launch_bounds__(256) void select_finalize_kernel(
    const float* __restrict__ logits,
    const float* __restrict__ weights,
    float* __restrict__ mask,       // -> d_out + 0
    float* __restrict__ aux)        // -> d_out + 2*BATCH*SEQ
{
    if (blockIdx.x == BATCH * 64) {
        // ---- variance block (256 threads, fp64) ----
        const int n = BATCH * SEQ;
        double s = 0.0, s2 = 0.0;
        for (int i = threadIdx.x; i < n; i += 256) {
            double w = (double)weights[i];
            s  += w;
            s2 += w * w;
        }
#pragma unroll
        for (int off = 32; off > 0; off >>= 1) {
            s  += __shfl_down(s,  off, 64);
            s2 += __shfl_down(s2, off, 64);
        }
        __shared__ double sh[8];
        const int wid  = threadIdx.x >> 6;
        const int lane = threadIdx.x & 63;
        if (lane == 0) { sh[wid] = s; sh[wid + 4] = s2; }
        __syncthreads();
        if (threadIdx.x == 0) {
            double S  = sh[0] + sh[1] + sh[2] + sh[3];
            double S2 = sh[4] + sh[5] + sh[6] + sh[7];
            double mean = S / n;
            double var  = (S2 - (double)n * mean * mean) / (double)(n - 1);
            *aux = (float)var;
        }
        return;
    }

    const int b    = blockIdx.x >> 6;    // batch
    const int eblk = blockIdx.x & 63;    // element chunk (64 elements)

    __shared__ float L[SEQ];
    __shared__ int sh_gt[64][5];         // [e][slice], stride 5 (odd) -> no conflicts
    __shared__ int sh_eq[64][5];

    const float* row = logits + b * SEQ;
    for (int i = threadIdx.x; i < SEQ / 4; i += 256)
        reinterpret_cast<float4*>(L)[i] =
            reinterpret_cast<const float4*>(row)[i];
    __syncthreads();

    const int e     = threadIdx.x & 63;
    const int slice = threadIdx.x >> 6;
    const int i     = eblk * 64 + e;
    const float v   = L[i];

    int gt = 0, eq = 0;
    const int j0 = slice * (SEQ / 4);
#pragma unroll 4
    for (int j = j0; j < j0 + SEQ / 4; j += 4) {
        float4 q = *reinterpret_cast<const float4*>(&L[j]);
        gt += (q.x > v) + (q.y > v) + (q.z > v) + (q.w > v);
        eq += (q.x == v) + (q.y == v) + (q.z == v) + (q.w == v);
    }
    sh_gt[e][slice] = gt;
    sh_eq[e][slice] = eq;
    __syncthreads();

    if (slice == 0) {
        const int GT = sh_gt[e][0] + sh_gt[e][1] + sh_gt[e][2] + sh_gt[e][3];
        const int EQ = sh_eq[e][0] + sh_eq[e][1] + sh_eq[e][2] + sh_eq[e][3]; // incl. self
        float m;
        if (GT >= KSEL) {
            m = 0.0f;
        } else if (EQ == 1) {
            m = 1.0f;                  // unique value, strictly inside top-K
        } else {
            // Rare tie path: jax top_k takes ties in increasing index order.
            int lower = 0;
            for (int j = 0; j < i; ++j) lower += (L[j] == v);
            m = (GT + lower < KSEL) ? 1.0f : 0.0f;
        }
        mask[b * SEQ + i] = m;
    }
}

extern "C" void kernel_launch(void* const* d_in, const int* in_sizes, int n_in,
                              void* d_out, int out_size, void* d_ws, size_t ws_size,
                              hipStream_t stream) {
    const float* x      = (const float*)d_in[0];   // [4,4096,2048] f32
    const float* gate_w = (const float*)d_in[1];   // [2048] f32

    float* out     = (float*)d_out;
    float* mask    = out;                          // [4,4096,1]
    float* weights = out + BATCH * SEQ;            // [4,4096,1]
    float* aux     = out + 2 * BATCH * SEQ;        // [1]

    float* logits = (float*)d_ws;                  // [4*4096] scratch

    // K1: logits + weights  (1024 blocks x 4 waves x 4 rows/wave = 16384 rows)
    logits_kernel<<<dim3(BATCH * SEQ / (4 * ROWS_PER_WAVE)), dim3(256), 0, stream>>>(
        x, gate_w, logits, weights);

    // K2: top-K mask per batch + variance (one extra block)
    select_finalize_kernel<<<dim3(BATCH * 64 + 1), dim3(256), 0, stream>>>(
        logits, weights, mask, aux);
}

// Round 4
// 39.289 us; speedup vs baseline: 1.1667x; 1.1667x over previous
//
#include <hip/hip_runtime.h>
#include <hip/hip_bf16.h>

// Problem constants (from reference setup_inputs: b=4, s=4096, d=2048, CAPACITY=0.5)
#define BATCH 4
#define SEQ   4096
#define DMODEL 2048
#define KSEL  2048   // max(1, int(SEQ*0.5))

// ---------------------------------------------------------------------------
// Kernel 1: logits = x @ gate_w (fp64 accumulate), weights = sigmoid(logits)
// 2048 blocks x 256 threads; each 64-lane wave owns 2 consecutive rows.
// gate_w (8 float4/lane = 32 VGPR) loaded once per wave. Per row: 8 float4
// x-loads then 32 fp64 FMAs (4 independent chains). ~110 VGPRs -> 4 waves/EU
// without spilling (R3's 4-row variant spilled under launch_bounds(256,4)).
// Two fp64 shuffle-reduce chains interleaved -> half the serial tails of R2.
// ---------------------------------------------------------------------------
__global__ __launch_bounds__(256) void logits_kernel(
    const float* __restrict__ x,
    const float* __restrict__ gate_w,
    float* __restrict__ logits,     // [BATCH*SEQ] in workspace
    float* __restrict__ weights)    // [BATCH*SEQ] -> d_out + BATCH*SEQ
{
    const int wave = threadIdx.x >> 6;
    const int lane = threadIdx.x & 63;
    const int wid  = blockIdx.x * 4 + wave;          // 0 .. 8191
    const int row0 = wid * 2;                        // 2 consecutive rows

    const float4* wr = reinterpret_cast<const float4*>(gate_w);
    float4 wv[8];
#pragma unroll
    for (int t = 0; t < 8; ++t) wv[t] = wr[t * 64 + lane];

    double rsum[2];
#pragma unroll
    for (int r = 0; r < 2; ++r) {
        const float4* xr =
            reinterpret_cast<const float4*>(x + (size_t)(row0 + r) * DMODEL);
        float4 xv[8];
#pragma unroll
        for (int t = 0; t < 8; ++t) xv[t] = xr[t * 64 + lane];

        double a0 = 0.0, a1 = 0.0, a2 = 0.0, a3 = 0.0;
#pragma unroll
        for (int t = 0; t < 8; ++t) {
            a0 += (double)xv[t].x * (double)wv[t].x;
            a1 += (double)xv[t].y * (double)wv[t].y;
            a2 += (double)xv[t].z * (double)wv[t].z;
            a3 += (double)xv[t].w * (double)wv[t].w;
        }
        rsum[r] = (a0 + a1) + (a2 + a3);
    }

    // 64-lane reduction, 2 independent fp64 chains interleaved
#pragma unroll
    for (int off = 32; off > 0; off >>= 1) {
        rsum[0] += __shfl_down(rsum[0], off, 64);
        rsum[1] += __shfl_down(rsum[1], off, 64);
    }

    if (lane == 0) {
#pragma unroll
        for (int r = 0; r < 2; ++r) {
            float l = (float)rsum[r];
            logits[row0 + r]  = l;
            weights[row0 + r] = 1.0f / (1.0f + expf(-l));
        }
    }
}

// ---------------------------------------------------------------------------
// Kernel 2 (merged select + finalize), 512 threads/block:
//   blocks 0 .. BATCH*64-1 : top-K mask via exact rank counting
//   block  BATCH*64        : aux_loss = unbiased variance of weights
// Mask blocks: full 4096-float row staged in LDS; thread (e = tid&63,
// slice = tid>>6, 8 slices) compares its element against 1/8 of the row via
// wave-uniform float4 LDS reads (broadcast, conflict-free). 512 compares per
// thread (was 1024) and 2 waves/SIMD for latency overlap. Tie-break matches
// jax.lax.top_k (lower index wins) via the rare-path recount.
// ---------------------------------------------------------------------------
__global__ __launch_bounds__(512) void select_finalize_kernel(
    const float* __restrict__ logits,
    const float* __restrict__ weights,
    float* __restrict__ mask,       // -> d_out + 0
    float* __restrict__ aux)        // -> d_out + 2*BATCH*SEQ
{
    if (blockIdx.x == BATCH * 64) {
        // ---- variance block (512 threads, fp64) ----
        const int n = BATCH * SEQ;
        double s = 0.0, s2 = 0.0;
        for (int i = threadIdx.x; i < n; i += 512) {
            double w = (double)weights[i];
            s  += w;
            s2 += w * w;
        }
#pragma unroll
        for (int off = 32; off > 0; off >>= 1) {
            s  += __shfl_down(s,  off, 64);
            s2 += __shfl_down(s2, off, 64);
        }
        __shared__ double sh[16];
        const int wid  = threadIdx.x >> 6;
        const int lane = threadIdx.x & 63;
        if (lane == 0) { sh[wid] = s; sh[wid + 8] = s2; }
        __syncthreads();
        if (threadIdx.x == 0) {
            double S = 0.0, S2 = 0.0;
#pragma unroll
            for (int w = 0; w < 8; ++w) { S += sh[w]; S2 += sh[w + 8]; }
            double mean = S / n;
            double var  = (S2 - (double)n * mean * mean) / (double)(n - 1);
            *aux = (float)var;
        }
        return;
    }

    const int b    = blockIdx.x >> 6;    // batch
    const int eblk = blockIdx.x & 63;    // element chunk (64 elements)

    __shared__ float L[SEQ];
    __shared__ int sh_gt[64][9];         // [e][slice], stride 9 (odd) -> 2-way max
    __shared__ int sh_eq[64][9];

    const float* row = logits + b * SEQ;
    for (int i = threadIdx.x; i < SEQ / 4; i += 512)
        reinterpret_cast<float4*>(L)[i] =
            reinterpret_cast<const float4*>(row)[i];
    __syncthreads();

    const int e     = threadIdx.x & 63;
    const int slice = threadIdx.x >> 6;  // 0..7
    const int i     = eblk * 64 + e;
    const float v   = L[i];

    int gt = 0, eq = 0;
    const int j0 = slice * (SEQ / 8);
#pragma unroll 4
    for (int j = j0; j < j0 + SEQ / 8; j += 4) {
        float4 q = *reinterpret_cast<const float4*>(&L[j]);
        gt += (q.x > v) + (q.y > v) + (q.z > v) + (q.w > v);
        eq += (q.x == v) + (q.y == v) + (q.z == v) + (q.w == v);
    }
    sh_gt[e][slice] = gt;
    sh_eq[e][slice] = eq;
    __syncthreads();

    if (slice == 0) {
        int GT = 0, EQ = 0;
#pragma unroll
        for (int t = 0; t < 8; ++t) { GT += sh_gt[e][t]; EQ += sh_eq[e][t]; }
        float m;
        if (GT >= KSEL) {
            m = 0.0f;
        } else if (EQ == 1) {
            m = 1.0f;                  // unique value, strictly inside top-K
        } else {
            // Rare tie path: jax top_k takes ties in increasing index order.
            int lower = 0;
            for (int j = 0; j < i; ++j) lower += (L[j] == v);
            m = (GT + lower < KSEL) ? 1.0f : 0.0f;
        }
        mask[b * SEQ + i] = m;
    }
}

extern "C" void kernel_launch(void* const* d_in, const int* in_sizes, int n_in,
                              void* d_out, int out_size, void* d_ws, size_t ws_size,
                              hipStream_t stream) {
    const float* x      = (const float*)d_in[0];   // [4,4096,2048] f32
    const float* gate_w = (const float*)d_in[1];   // [2048] f32

    float* out     = (float*)d_out;
    float* mask    = out;                          // [4,4096,1]
    float* weights = out + BATCH * SEQ;            // [4,4096,1]
    float* aux     = out + 2 * BATCH * SEQ;        // [1]

    float* logits = (float*)d_ws;                  // [4*4096] scratch

    // K1: logits + weights  (2048 blocks x 4 waves x 2 rows/wave = 16384 rows)
    logits_kernel<<<dim3(BATCH * SEQ / 8), dim3(256), 0, stream>>>(
        x, gate_w, logits, weights);

    // K2: top-K mask per batch + variance (one extra block)
    select_finalize_kernel<<<dim3(BATCH * 64 + 1), dim3(512), 0, stream>>>(
        logits, weights, mask, aux);
}